// Round 14
// baseline (129.764 us; speedup 1.0000x reference)
//
#include <hip/hip_runtime.h>
#include <hip/hip_bf16.h>

// ---------------------------------------------------------------------------
// HiddenEdgeDistanceMLP on MI355X (gfx950)
//
// reference:  s = s_lig[l] + s_poc[p]          [E,256]
//             h1 = silu(s @ W1.T + b1)         [E,128]
//             h2 = silu(h1 @ W2.T + b2)        [E,64]
//             out = relu(h2 @ W3.T + b3)       [E]
//
// v26 (R13): BF16 POCKET-Z. R12's flatness (proj compute cut -> 0 gain)
//   proves proj is MEMORY-bound (~37 MB @ ~2.5 TB/s eff). Cut its bytes:
//   - Z splits: Zl f32 (2 MB, ligand, exact hi/lo path untouched) +
//     Zp bf16 (5.2 MB, pocket: zero-reuse rows, A already single-bf16).
//     Proj writes 12.6 -> 7.2 MB; edge FETCH 13.6 -> ~8.5 MB.
//   - Pocket store via SWAPPED MFMA (bitwise transpose, proven in edge
//     since R9): lane holds n = half*64+nt*16+q*4+r for row m = tile*16+c
//     -> 4x 8-B uintx2 stores/thread (was 16 scattered dwords).
//   - Edge zp staging expands bf16->f32 at stage time (4 lshl/thread);
//     main loop byte-identical to v23/v25.
//   Numerics: zp gains ±2^-9*|Z| (~2e-3 on silu input) — same order as
//   R12's A-rounding which left absmax unchanged. Expect ~0.002-0.004 PASS.
// v25/v23 mechanisms kept: edge VERBATIM except zp staging; Z pre-scaled
//   x(-log2e), W2F pre-converted, 512-thr edge blocks (8w x 4 atoms),
//   swapped D^T epilogue, exp2 silu, RNE cvt_pk, grid 1280, one barrier.
// ---------------------------------------------------------------------------

#define B_CPLX   128
#define NLB      32
#define NPB      160
#define SDIM     256
#define H1DIM    128
#define NL_TOT   (B_CPLX * NLB)         // 4096
#define NP_TOT   (B_CPLX * NPB)         // 20480
#define NROWS    (NL_TOT + NP_TOT)      // 24576
#define E_TOT    (B_CPLX * NLB * NPB)   // 655360

#define W1_LDS_STRIDE 264               // 256 + 8 bf16 pad
#define JT_CHUNK 16                     // pocket rows per block
#define ZP_STRIDE 132                   // 128 + 4 f32 pad (bank spread)

#define EDGE_BLOCKS (B_CPLX * 10)       // 1280 = (b, jt)

#define LIG_TG 64                       // tile-groups 0..63 are ligand rows

#define NEG_LOG2E -1.4426950408889634f  // -log2(e)
#define NEG_LN2   -0.69314718055994531f // -ln(2)

typedef __bf16 bf16x8 __attribute__((ext_vector_type(8)));
typedef __bf16 bf16x2 __attribute__((ext_vector_type(2)));
typedef unsigned short ushortx8 __attribute__((ext_vector_type(8)));
typedef unsigned short ushortx4 __attribute__((ext_vector_type(4)));
typedef unsigned uintx4 __attribute__((ext_vector_type(4)));
typedef unsigned uintx2 __attribute__((ext_vector_type(2)));
typedef float f32x4 __attribute__((ext_vector_type(4)));
typedef float f32x2 __attribute__((ext_vector_type(2)));

#if __has_builtin(__builtin_amdgcn_exp2f)
#define EXP2F(x) __builtin_amdgcn_exp2f(x)
#else
#define EXP2F(x) exp2f(x)
#endif

// v_perm_b32: pack hi16(x0) low, hi16(x1) high (1 op)
__device__ __forceinline__ unsigned perm_hi16u(unsigned u0, unsigned u1) {
    return __builtin_amdgcn_perm(u1, u0, 0x07060302u);
}

// RNE pair-convert via HW v_cvt_pk_bf16_f32 -> packed u32
__device__ __forceinline__ unsigned cvt2_rne(float x0, float x1) {
    f32x2 p = {x0, x1};
    bf16x2 b = __builtin_convertvector(p, bf16x2);
    return __builtin_bit_cast(unsigned, b);
}

// f32x4 -> 4 bf16 (RNE, 2 cvt_pk ops), as uintx2
__device__ __forceinline__ uintx2 pack4_rne_u(f32x4 v) {
    uintx2 r;
    r[0] = cvt2_rne(v[0], v[1]);
    r[1] = cvt2_rne(v[2], v[3]);
    return r;
}

// RNE pack of 8 floats via cvt_pk (compiler-lowered, no inline asm)
__device__ __forceinline__ bf16x8 pack8_rne(const float* x) {
    uintx4 h;
#pragma unroll
    for (int j = 0; j < 4; ++j) h[j] = cvt2_rne(x[2 * j], x[2 * j + 1]);
    return __builtin_bit_cast(bf16x8, h);
}

// hi/lo split (ligand proj path): hi = trunc bf16 (perm), lo = RNE bf16(x-hi)
__device__ __forceinline__ void pack_split(const float* x, bf16x8& hi, bf16x8& lo) {
    uintx4 h, l;
#pragma unroll
    for (int j = 0; j < 4; ++j) {
        float x0 = x[2 * j], x1 = x[2 * j + 1];
        unsigned u0 = __builtin_bit_cast(unsigned, x0);
        unsigned u1 = __builtin_bit_cast(unsigned, x1);
        h[j] = perm_hi16u(u0, u1);
        float hf0 = __builtin_bit_cast(float, u0 & 0xFFFF0000u);
        float hf1 = __builtin_bit_cast(float, u1 & 0xFFFF0000u);
        l[j] = cvt2_rne(x0 - hf0, x1 - hf1);
    }
    hi = __builtin_bit_cast(bf16x8, h);
    lo = __builtin_bit_cast(bf16x8, l);
}

// pre-scaled silu: t = -log2e * s  ->  u = t * sigma(s) = -log2e * silu(s)
__device__ __forceinline__ float silu_u(float t) {
    float e = EXP2F(t);
    float r = __builtin_amdgcn_rcpf(1.0f + e);
    return t * r;
}

// ---------------------------------------------------------------------------
// Kernel 1: Zl[m][n] (f32, ligand, hi/lo exact) and Zp[mp][n] (bf16, pocket,
//   single-RNE A, SWAPPED-MFMA store). Both pre-scaled x(-log2e); b1 folded
//   into ligand only. Block 0 also writes frag-ordered bf16 W2 -> W2F.
// ---------------------------------------------------------------------------
__global__ __launch_bounds__(256) void proj_kernel(
    const float* __restrict__ s_lig, const float* __restrict__ s_poc,
    const float* __restrict__ W1,    const float* __restrict__ b1,
    const float* __restrict__ W2,
    float* __restrict__ Zl,          unsigned short* __restrict__ Zp,
    unsigned short* __restrict__ W2F)
{
    __shared__ unsigned short w1s[64 * W1_LDS_STRIDE];   // 33.8 KB

    const int tid  = threadIdx.x;
    const int tg   = blockIdx.x >> 1;             // row-tile group 0..383
    const int half = blockIdx.x & 1;              // N half
    const bool is_lig = (tg < LIG_TG);            // block-uniform

    // block 0 extra duty: frag-ordered bf16 W2 -> workspace (RNE)
    if (blockIdx.x == 0) {
#pragma unroll
        for (int s = 0; s < 4; ++s) {
            const int slot   = tid + s * 256;             // 0..1023
            const int lane_s = slot & 63;
            const int chunk  = slot >> 6;
            const int nt     = chunk >> 2;
            const int ks     = chunk & 3;
            const int n      = nt * 16 + (lane_s & 15);
            const int k0     = ks * 32 + (lane_s >> 4) * 8;
            const float* wsrc = W2 + (size_t)n * H1DIM + k0;
            f32x4 wa = *(const f32x4*)wsrc;
            f32x4 wb = *(const f32x4*)(wsrc + 4);
            uintx4 us;
            us[0] = cvt2_rne(wa[0], wa[1]);
            us[1] = cvt2_rne(wa[2], wa[3]);
            us[2] = cvt2_rne(wb[0], wb[1]);
            us[3] = cvt2_rne(wb[2], wb[3]);
            *(uintx4*)(&W2F[slot * 8]) = us;
        }
    }

    {
        const f32x4* w4 = (const f32x4*)(W1 + (size_t)half * 64 * SDIM);  // 4096 units
#pragma unroll
        for (int r = 0; r < 2; ++r) {
            f32x4 t[8];
#pragma unroll
            for (int s = 0; s < 8; ++s) t[s] = w4[tid + (r * 8 + s) * 256];
#pragma unroll
            for (int s = 0; s < 8; ++s) {
                const int u = tid + (r * 8 + s) * 256;
                const int n = u >> 6;             // 64 f32x4 per 256-col row
                const int k4 = u & 63;
                uintx2 us = pack4_rne_u(t[s] * NEG_LOG2E);   // 2 cvt_pk + 1 pk-mul
                *(uintx2*)(&w1s[n * W1_LDS_STRIDE + k4 * 4]) = us;
            }
        }
    }
    __syncthreads();

    const int lane = tid & 63;
    const int widx = tid >> 6;
    const int c    = lane & 15;
    const int q    = lane >> 4;
    const int tile = tg * 4 + widx;               // 0..1535
    const int row  = tile * 16 + c;

    const float* src = is_lig ? (s_lig + (size_t)row * SDIM)
                              : (s_poc + (size_t)(row - NL_TOT) * SDIM);

    f32x4 acc[4];
#pragma unroll
    for (int nt = 0; nt < 4; ++nt) acc[nt] = (f32x4){0.f, 0.f, 0.f, 0.f};

#pragma unroll
    for (int ks = 0; ks < 8; ++ks) {              // K = 256 = 8 x 32
        const int k0 = ks * 32 + q * 8;
        f32x4 xa = *reinterpret_cast<const f32x4*>(src + k0);
        f32x4 xb = *reinterpret_cast<const f32x4*>(src + k0 + 4);
        float xv[8] = {xa[0], xa[1], xa[2], xa[3], xb[0], xb[1], xb[2], xb[3]};
        bf16x8 bfrag[4];
#pragma unroll
        for (int nt = 0; nt < 4; ++nt)
            bfrag[nt] = *reinterpret_cast<const bf16x8*>(
                &w1s[(nt * 16 + c) * W1_LDS_STRIDE + k0]);
        if (is_lig) {                             // exact hi/lo path (x10 reuse)
            bf16x8 ahi, alo;
            pack_split(xv, ahi, alo);
#pragma unroll
            for (int nt = 0; nt < 4; ++nt)        // hi pass (dep distance 4)
                acc[nt] = __builtin_amdgcn_mfma_f32_16x16x32_bf16(ahi, bfrag[nt], acc[nt], 0, 0, 0);
#pragma unroll
            for (int nt = 0; nt < 4; ++nt)        // lo pass
                acc[nt] = __builtin_amdgcn_mfma_f32_16x16x32_bf16(alo, bfrag[nt], acc[nt], 0, 0, 0);
        } else {                                  // pocket: single RNE bf16,
            bf16x8 af = pack8_rne(xv);            // SWAPPED operands -> D^T
#pragma unroll
            for (int nt = 0; nt < 4; ++nt)
                acc[nt] = __builtin_amdgcn_mfma_f32_16x16x32_bf16(bfrag[nt], af, acc[nt], 0, 0, 0);
        }
    }

    if (is_lig) {
        // D layout: col n' = lane&15, row m = q*4 + reg
        const int mb = tile * 16 + q * 4;
#pragma unroll
        for (int nt = 0; nt < 4; ++nt) {
            const int n = half * 64 + nt * 16 + c;
            const float bias = b1[n] * NEG_LOG2E; // scaled bias (Z pre-scaled)
#pragma unroll
            for (int r = 0; r < 4; ++r)
                Zl[(size_t)(mb + r) * H1DIM + n] = acc[nt][r] + bias;
        }
    } else {
        // SWAPPED D: lane holds n = half*64 + nt*16 + q*4 + r for pocket
        // row m = tile*16 + c. 4x 8-B bf16 stores (no bias on pocket rows).
        const int mp = tile * 16 + c - NL_TOT;    // pocket row index
        unsigned short* zpr = Zp + (size_t)mp * H1DIM + half * 64 + q * 4;
#pragma unroll
        for (int nt = 0; nt < 4; ++nt)
            *(uintx2*)(zpr + nt * 16) = pack4_rne_u(acc[nt]);
    }
}

// ---------------------------------------------------------------------------
// Kernel 2 (v23 VERBATIM except zp staging reads bf16 Zp): block = (b, jt);
//   1280 blocks x 512 threads (8 waves). Wave widx owns atoms widx*4..+3.
//   One barrier; SWAPPED D^T MFMA epilogue.
// ---------------------------------------------------------------------------
__global__ __launch_bounds__(512) void edge_kernel(
    const float* __restrict__ Zl, const unsigned short* __restrict__ Zp,
    const unsigned short* __restrict__ W2F,
    const float* __restrict__ b2, const float* __restrict__ W3,
    const float* __restrict__ b3, float* __restrict__ out)
{
    __shared__ float zp[JT_CHUNK * ZP_STRIDE];            // 8.4 KB (expanded)
    __shared__ float zl[NLB * H1DIM];                     // 16 KB (pre-scaled)
    __shared__ unsigned short w2s[16 * 64 * 8];           // 16 KB frag-ordered

    const int tid = threadIdx.x;                  // 0..511
    const int b   = blockIdx.x / 10;
    const int jt  = blockIdx.x - b * 10;          // 0..9

    // stage W2 fragments: pure 16B copies from the precomputed region
    {
#pragma unroll
        for (int s = 0; s < 2; ++s) {
            const int slot = tid + s * 512;               // 0..1023
            *(ushortx8*)(&w2s[slot * 8]) = *(const ushortx8*)(&W2F[slot * 8]);
        }
    }

    // stage pocket rows from bf16 Zp: 2048 ushorts; thread loads 4 (8 B),
    // expands bf16->f32 (lshl 16), writes 16 B to LDS.
    {
        const unsigned short* zpg = Zp + (size_t)(b * NPB + jt * JT_CHUNK) * H1DIM;
        const int row = tid >> 5;                 // 0..15
        const int c4  = tid & 31;
        ushortx4 u = *(const ushortx4*)(zpg + (size_t)row * H1DIM + c4 * 4);
        f32x4 f;
#pragma unroll
        for (int j = 0; j < 4; ++j)
            f[j] = __builtin_bit_cast(float, (unsigned)u[j] << 16);
        *(f32x4*)(&zp[row * ZP_STRIDE + c4 * 4]) = f;
    }

    // stage ALL 32 ligand rows (pre-scaled f32): pure copy, 2 f32x4/thread
    {
        const float* zlg = Zl + (size_t)(b * NLB) * H1DIM;
#pragma unroll
        for (int s = 0; s < 2; ++s) {
            const int u   = tid + s * 512;                // 0..1023
            const int row = u >> 5;
            const int c4  = u & 31;
            *(f32x4*)(&zl[row * H1DIM + c4 * 4]) =
                *(const f32x4*)(zlg + (size_t)row * H1DIM + c4 * 4);
        }
    }

    const int lane = tid & 63;
    const int widx = tid >> 6;                    // 0..7
    const int c    = lane & 15;
    const int q    = lane >> 4;

    // swapped-D layout: lane reg (nt, r) <-> h2 channel m = nt*16 + q*4 + r.
    // b2 scaled by -log2e (acc accumulates t2); W3 scaled by -ln2.
    f32x4 b2v[4], w3v[4];
#pragma unroll
    for (int nt = 0; nt < 4; ++nt) {
        f32x4 bv = *(const f32x4*)(b2 + nt * 16 + q * 4);
        f32x4 wv = *(const f32x4*)(W3 + nt * 16 + q * 4);
        b2v[nt] = bv * NEG_LOG2E;
        w3v[nt] = wv * NEG_LN2;
    }
    const float b3v = b3[0];

    __syncthreads();   // w2s + zp + zl visible; the ONLY barrier

    const float* prow = &zp[c * ZP_STRIDE];
    const unsigned short* wbase = &w2s[lane * 8];          // + chunk*512 ushorts

    // acc init = -log2e * b2 (per-channel, vectorized over r)
    f32x4 acc[4][4];                               // [atom][nt]
#pragma unroll
    for (int a = 0; a < 4; ++a)
#pragma unroll
        for (int nt = 0; nt < 4; ++nt) acc[a][nt] = b2v[nt];

    // wave's 4 atoms: widx*4 + a
    const float* lrow0 = &zl[(widx * 4) * H1DIM];

#pragma unroll
    for (int ks = 0; ks < 4; ++ks) {               // K = 128 = 4 x 32
        const int k0 = ks * 32 + q * 8;
        bf16x8 bfr[4];
#pragma unroll
        for (int nt = 0; nt < 4; ++nt)             // conflict-free ds_read_b128
            bfr[nt] = *(const bf16x8*)(wbase + (nt * 4 + ks) * 512);
        f32x4 pa = *(const f32x4*)(prow + k0);
        f32x4 pb = *(const f32x4*)(prow + k0 + 4);
#pragma unroll
        for (int a = 0; a < 4; ++a) {              // 4 atoms share bfr/pa/pb
            f32x4 la0 = *(const f32x4*)(lrow0 + a * H1DIM + k0);
            f32x4 la1 = *(const f32x4*)(lrow0 + a * H1DIM + k0 + 4);
            float hv[8];
#pragma unroll
            for (int j = 0; j < 4; ++j) {          // u = -log2e * silu(s)
                hv[j]     = silu_u(pa[j] + la0[j]);
                hv[4 + j] = silu_u(pb[j] + la1[j]);
            }
            bf16x8 af = pack8_rne(hv);
#pragma unroll
            for (int nt = 0; nt < 4; ++nt)         // SWAPPED: D^T, bitwise
                acc[a][nt] = __builtin_amdgcn_mfma_f32_16x16x32_bf16(bfr[nt], af, acc[a][nt], 0, 0, 0);
        }
    }

    // epilogue: lane holds t2 for channels m=nt*16+q*4+r, pocket c.
    // dot(silu_u(t2), w3v) per lane -> sum over q via shfl_xor 16/32.
#pragma unroll
    for (int at = 0; at < 4; ++at) {
        const f32x4* A = acc[at];
        float s0 = 0.f, s1 = 0.f, s2 = 0.f, s3 = 0.f;
#pragma unroll
        for (int nt = 0; nt < 4; ++nt) {           // u2 = -log2e*silu(h2pre)
            s0 += silu_u(A[nt][0]) * w3v[nt][0];
            s1 += silu_u(A[nt][1]) * w3v[nt][1];
            s2 += silu_u(A[nt][2]) * w3v[nt][2];
            s3 += silu_u(A[nt][3]) * w3v[nt][3];
        }
        float v = (s0 + s1) + (s2 + s3);           // per-lane partial (16 ch)
        v += __shfl_xor(v, 16);                    // q ^ 1
        v += __shfl_xor(v, 32);                    // q ^ 2 -> all 64 channels
        if (lane < 16) {
            const int e0 = (b * NLB + widx * 4 + at) * NPB + jt * JT_CHUNK;
            out[e0 + lane] = fmaxf(v + b3v, 0.0f); // 64B coalesced
        }
    }
}

// ---------------------------------------------------------------------------
extern "C" void kernel_launch(void* const* d_in, const int* in_sizes, int n_in,
                              void* d_out, int out_size, void* d_ws, size_t ws_size,
                              hipStream_t stream)
{
    const float* s_lig = (const float*)d_in[0];
    const float* s_poc = (const float*)d_in[1];
    const float* W1    = (const float*)d_in[4];
    const float* b1    = (const float*)d_in[5];
    const float* W2    = (const float*)d_in[6];
    const float* b2    = (const float*)d_in[7];
    const float* W3    = (const float*)d_in[8];
    const float* b3    = (const float*)d_in[9];

    float* Zl = (float*)d_ws;                                  // 2 MB f32
    unsigned short* Zp  = (unsigned short*)(Zl + (size_t)NL_TOT * H1DIM);  // 5.24 MB bf16
    unsigned short* W2F = Zp + (size_t)NP_TOT * H1DIM;                     // +16 KB

    hipLaunchKernelGGL(proj_kernel, dim3(NROWS / 16 / 4 * 2), dim3(256), 0, stream,
                       s_lig, s_poc, W1, b1, W2, Zl, Zp, W2F);
    hipLaunchKernelGGL(edge_kernel, dim3(EDGE_BLOCKS), dim3(512), 0, stream,
                       Zl, Zp, W2F, b2, W3, b3, (float*)d_out);
}